// Round 1
// baseline (404.019 us; speedup 1.0000x reference)
//
#include <hip/hip_runtime.h>
#include <math.h>

// Problem constants
constexpr int B  = 4;
constexpr int S  = 2048;
constexpr int DM = 1024;
constexpr int DK = 128;
constexpr int BS = B * S;

static constexpr float SCALE = 0.08838834764831845f; // 1/sqrt(128)

// ---------------------------------------------------------------------------
// Kernel A: projections (q,k,v) = value_in @ [w_q | w_k | w_v]
// M=8192, N=384, K=1024, split-K=2 for balance (256 blocks).
// Tile: 64 rows x 384 cols, BK=32. Thread micro-tile 4x24.
// Writes partial sums [kc][row][384] (reduced by reduce_kernel).
// ---------------------------------------------------------------------------
__global__ __launch_bounds__(256) void proj_kernel(
    const float* __restrict__ vin, const float* __restrict__ wq,
    const float* __restrict__ wk, const float* __restrict__ wv,
    float* __restrict__ part)
{
  const int r0 = blockIdx.x * 64;
  const int kc = blockIdx.y;            // 0..1 (K chunk)
  const int k_base = kc * 512;

  __shared__ float As[64][33];          // 64 rows x 32 k (pad -> conflict-free)
  __shared__ float Ws[32][388];         // 32 k x 384 cols (pad 4)

  const int t  = threadIdx.x;
  const int ty = t >> 4, tx = t & 15;

  float acc[4][24];
  #pragma unroll
  for (int i = 0; i < 4; ++i)
    #pragma unroll
    for (int j = 0; j < 24; ++j) acc[i][j] = 0.f;

  for (int k0 = 0; k0 < 512; k0 += 32) {
    // Load A tile 64x32 (coalesced: 32 consecutive k per row)
    {
      const int kk = t & 31, r = t >> 5;
      #pragma unroll
      for (int i = 0; i < 8; ++i)
        As[r + i * 8][kk] = vin[(size_t)(r0 + r + i * 8) * DM + k_base + k0 + kk];
    }
    // Load W tiles 32x128 for each of 3 projections
    {
      const int c = t & 127, kr = t >> 7; // kr 0..1
      const float* Wp[3] = {wq, wk, wv};
      #pragma unroll
      for (int p = 0; p < 3; ++p)
        #pragma unroll
        for (int i = 0; i < 16; ++i)
          Ws[kr + i * 2][p * 128 + c] = Wp[p][(size_t)(k_base + k0 + kr + i * 2) * DK + c];
    }
    __syncthreads();
    #pragma unroll 4
    for (int kk = 0; kk < 32; ++kk) {
      float a[4], w[24];
      #pragma unroll
      for (int i = 0; i < 4; ++i) a[i] = As[ty * 4 + i][kk];
      #pragma unroll
      for (int j = 0; j < 24; ++j) w[j] = Ws[kk][tx + 16 * j];
      #pragma unroll
      for (int i = 0; i < 4; ++i)
        #pragma unroll
        for (int j = 0; j < 24; ++j)
          acc[i][j] += a[i] * w[j];
    }
    __syncthreads();
  }

  float* pb = part + (size_t)kc * BS * 384;
  #pragma unroll
  for (int i = 0; i < 4; ++i)
    #pragma unroll
    for (int j = 0; j < 24; ++j)
      pb[(size_t)(r0 + ty * 4 + i) * 384 + tx + 16 * j] = acc[i][j];
}

// Reduce the 2 K-chunks; rearrange [row][p*128+c] -> qkv [p][row][c]
__global__ void reduce_kernel(const float* __restrict__ part, float* __restrict__ qkv)
{
  const int row = blockIdx.x;
  const int c   = threadIdx.x;          // 384 threads
  const float v = part[(size_t)row * 384 + c] +
                  part[(size_t)(BS + row) * 384 + c];
  qkv[(size_t)(c >> 7) * (BS * DK) + (size_t)row * DK + (c & 127)] = v;
}

// ---------------------------------------------------------------------------
// Kernel B: raw scores att[b][q][s] = (q.k)/sqrt(128) for lower-tri tiles.
// Masked entries (q<s) are never read downstream, so no -inf writes needed.
// Tile 64x64, K=128 in 2 stages of 64. Thread micro-tile 4x4.
// ---------------------------------------------------------------------------
__global__ __launch_bounds__(256) void scores_kernel(
    const float* __restrict__ qkv, float* __restrict__ att)
{
  const int st = blockIdx.x, qt = blockIdx.y, b = blockIdx.z;
  if (qt < st) return;                  // fully-masked tile
  const int q0 = qt * 64, s0 = st * 64;
  const float* qm = qkv + (size_t)b * S * DK;
  const float* km = qkv + (size_t)BS * DK + (size_t)b * S * DK;

  __shared__ float Qs[64][68];
  __shared__ float Ks[64][68];

  const int t  = threadIdx.x;
  const int ty = t >> 4, tx = t & 15;
  float acc[4][4] = {};

  for (int kt = 0; kt < 2; ++kt) {
    #pragma unroll
    for (int i = 0; i < 4; ++i) {
      int flat = t + i * 256;           // 1024 float4 loads per operand
      int row = flat >> 4, c4 = (flat & 15) * 4;
      *(float4*)&Qs[row][c4] = *(const float4*)&qm[(size_t)(q0 + row) * DK + kt * 64 + c4];
      *(float4*)&Ks[row][c4] = *(const float4*)&km[(size_t)(s0 + row) * DK + kt * 64 + c4];
    }
    __syncthreads();
    for (int kk = 0; kk < 64; ++kk) {
      float a[4], bb[4];
      #pragma unroll
      for (int i = 0; i < 4; ++i) a[i] = Qs[ty * 4 + i][kk];
      #pragma unroll
      for (int j = 0; j < 4; ++j) bb[j] = Ks[tx + 16 * j][kk];
      #pragma unroll
      for (int i = 0; i < 4; ++i)
        #pragma unroll
        for (int j = 0; j < 4; ++j)
          acc[i][j] += a[i] * bb[j];
    }
    __syncthreads();
  }

  float* attb = att + (size_t)b * S * S;
  #pragma unroll
  for (int i = 0; i < 4; ++i) {
    const size_t qi = q0 + ty * 4 + i;
    #pragma unroll
    for (int j = 0; j < 4; ++j)
      attb[qi * S + s0 + tx + 16 * j] = acc[i][j] * SCALE;
  }
}

// ---------------------------------------------------------------------------
// Kernel C: column softmax (softmax over q for each column s, causal q>=s)
// C1: per-(256-row chunk, column) online max/sum partials
// C2: combine 8 chunks -> column max m and 1/sum
// C3: write att = exp(score-m)/sum (or 0 where masked)
// ---------------------------------------------------------------------------
__global__ __launch_bounds__(256) void colstats_kernel(
    const float* __restrict__ att, float* __restrict__ pm, float* __restrict__ ps)
{
  const int s  = blockIdx.x * 256 + threadIdx.x;
  const int ch = blockIdx.y, b = blockIdx.z;
  const float* attb = att + (size_t)b * S * S;
  const int qlo = ch * 256, qhi = qlo + 256;
  float m = -INFINITY, sum = 0.f;
  for (int q = qlo; q < qhi; ++q) {
    if (q >= s) {
      const float x  = attb[(size_t)q * S + s];
      const float mn = fmaxf(m, x);
      sum = sum * __expf(m - mn) + __expf(x - mn);
      m = mn;
    }
  }
  const size_t idx = ((size_t)b * 8 + ch) * S + s;
  pm[idx] = m;
  ps[idx] = sum;
}

__global__ void colcombine_kernel(const float* __restrict__ pm, const float* __restrict__ ps,
                                  float* __restrict__ cm, float* __restrict__ cinv)
{
  const int s = blockIdx.x * 256 + threadIdx.x;
  const int b = blockIdx.y;
  float m = -INFINITY;
  for (int ch = 0; ch < 8; ++ch)
    m = fmaxf(m, pm[((size_t)b * 8 + ch) * S + s]);
  float sum = 0.f;
  for (int ch = 0; ch < 8; ++ch) {
    const size_t i = ((size_t)b * 8 + ch) * S + s;
    sum += ps[i] * __expf(pm[i] - m);
  }
  cm[(size_t)b * S + s]   = m;
  cinv[(size_t)b * S + s] = 1.f / sum;   // sum >= 1 (diagonal element)
}

__global__ __launch_bounds__(256) void colnorm_kernel(
    float* __restrict__ att, const float* __restrict__ cm, const float* __restrict__ cinv)
{
  const int s  = blockIdx.x * 256 + threadIdx.x;
  const int qt = blockIdx.y, b = blockIdx.z;
  float* attb = att + (size_t)b * S * S;
  const float m   = cm[(size_t)b * S + s];
  const float inv = cinv[(size_t)b * S + s];
  const int q0 = qt * 64;
  for (int q = q0; q < q0 + 64; ++q) {
    const size_t idx = (size_t)q * S + s;
    float x = 0.f;
    if (q >= s) x = __expf(attb[idx] - m) * inv;
    attb[idx] = x;
  }
}

// ---------------------------------------------------------------------------
// Kernel D: out[b][q][:] = sum_s att[b][q][s] * v[b][s][:]  (s <= q)
// Tile 32 q-rows x 128 v-cols, K-loop over s in steps of 64 (att is exactly 0
// above the diagonal after colnorm, so the ragged tail is free).
// ---------------------------------------------------------------------------
__global__ __launch_bounds__(256) void out_kernel(
    const float* __restrict__ att, const float* __restrict__ qkv, float* __restrict__ out)
{
  const int qt = blockIdx.x, b = blockIdx.y;
  const int q0 = qt * 32;
  const float* attb = att + (size_t)b * S * S;
  const float* vm   = qkv + 2ull * BS * DK + (size_t)b * S * DK;

  __shared__ float As[32][68];
  __shared__ float Vs[64][132];

  const int t  = threadIdx.x;
  const int ty = t >> 5, tx = t & 31;
  float acc[4][4] = {};

  for (int s0 = 0; s0 < q0 + 32; s0 += 64) {
    #pragma unroll
    for (int i = 0; i < 2; ++i) {
      int flat = t + i * 256;
      int row = flat >> 4, c4 = (flat & 15) * 4;
      *(float4*)&As[row][c4] = *(const float4*)&attb[(size_t)(q0 + row) * S + s0 + c4];
    }
    #pragma unroll
    for (int i = 0; i < 8; ++i) {
      int flat = t + i * 256;
      int row = flat >> 5, c4 = (flat & 31) * 4;
      *(float4*)&Vs[row][c4] = *(const float4*)&vm[(size_t)(s0 + row) * DK + c4];
    }
    __syncthreads();
    for (int kk = 0; kk < 64; ++kk) {
      float a[4], vv[4];
      #pragma unroll
      for (int i = 0; i < 4; ++i) a[i] = As[ty * 4 + i][kk];
      #pragma unroll
      for (int j = 0; j < 4; ++j) vv[j] = Vs[kk][tx + 32 * j];
      #pragma unroll
      for (int i = 0; i < 4; ++i)
        #pragma unroll
        for (int j = 0; j < 4; ++j)
          acc[i][j] += a[i] * vv[j];
    }
    __syncthreads();
  }

  #pragma unroll
  for (int i = 0; i < 4; ++i)
    #pragma unroll
    for (int j = 0; j < 4; ++j)
      out[((size_t)b * S + q0 + ty * 4 + i) * DK + tx + 32 * j] = acc[i][j];
}

// ---------------------------------------------------------------------------
extern "C" void kernel_launch(void* const* d_in, const int* in_sizes, int n_in,
                              void* d_out, int out_size, void* d_ws, size_t ws_size,
                              hipStream_t stream)
{
  const float* vin = (const float*)d_in[0];
  const float* wq  = (const float*)d_in[1];
  const float* wk  = (const float*)d_in[2];
  const float* wv  = (const float*)d_in[3];

  float* out = (float*)d_out;
  float* att = out + (size_t)B * S * DK;   // attention output region (64 MB)

  // Scratch layout. Projection partials (25 MB) live INSIDE the attention
  // output region: they are fully consumed by reduce_kernel before
  // scores_kernel overwrites att. d_ws only holds qkv + softmax stats (~13 MB).
  float* part = att;                        // 2 * BS * 384 floats (within att)
  float* qkv  = (float*)d_ws;               // 3 * BS * 128
  float* pm   = qkv + 3ull * BS * DK;       // B * 8 * S
  float* ps   = pm + 8ull * B * S;          // B * 8 * S
  float* cm   = ps + 8ull * B * S;          // B * S
  float* cinv = cm + (size_t)B * S;         // B * S

  proj_kernel      <<<dim3(BS / 64, 2),        256, 0, stream>>>(vin, wq, wk, wv, part);
  reduce_kernel    <<<dim3(BS),                384, 0, stream>>>(part, qkv);
  scores_kernel    <<<dim3(S / 64, S / 64, B), 256, 0, stream>>>(qkv, att);
  colstats_kernel  <<<dim3(S / 256, 8, B),     256, 0, stream>>>(att, pm, ps);
  colcombine_kernel<<<dim3(S / 256, B),        256, 0, stream>>>(pm, ps, cm, cinv);
  colnorm_kernel   <<<dim3(S / 256, S / 64, B),256, 0, stream>>>(att, cm, cinv);
  out_kernel       <<<dim3(S / 32, B),         256, 0, stream>>>(att, qkv, out);
}

// Round 2
// 312.993 us; speedup vs baseline: 1.2908x; 1.2908x over previous
//
#include <hip/hip_runtime.h>
#include <math.h>

// Problem constants
constexpr int B  = 4;
constexpr int S  = 2048;
constexpr int DM = 1024;
constexpr int DK = 128;
constexpr int BS = B * S;

static constexpr float SCALE = 0.08838834764831845f; // 1/sqrt(128)

typedef __attribute__((ext_vector_type(8))) short bf16x8;
typedef __attribute__((ext_vector_type(4))) float f32x4;

__device__ __forceinline__ unsigned short f2bf(float x) {
  unsigned u = __float_as_uint(x);
  unsigned r = (u + 0x7FFFu + ((u >> 16) & 1u)) >> 16;   // RNE
  return (unsigned short)r;
}
__device__ __forceinline__ float bf2f(unsigned short h) {
  return __uint_as_float(((unsigned)h) << 16);
}

__device__ __forceinline__ void gload16(const void* g, void* l) {
  __builtin_amdgcn_global_load_lds(
      (const __attribute__((address_space(1))) void*)g,
      (__attribute__((address_space(3))) void*)l, 16, 0, 0);
}

// ---------------------------------------------------------------------------
// Prep 1: vin fp32 -> Ah (bf16 RNE) + Al (bf16 of residual), row-major [BS][DM]
// ---------------------------------------------------------------------------
__global__ __launch_bounds__(256) void cvt_hilo(
    const float* __restrict__ x, unsigned short* __restrict__ hi,
    unsigned short* __restrict__ lo)
{
  const size_t idx = (size_t)blockIdx.x * 256 + threadIdx.x;  // float4 index
  const float4 v = ((const float4*)x)[idx];
  ushort4 h, l;
  h.x = f2bf(v.x); l.x = f2bf(v.x - bf2f(h.x));
  h.y = f2bf(v.y); l.y = f2bf(v.y - bf2f(h.y));
  h.z = f2bf(v.z); l.z = f2bf(v.z - bf2f(h.z));
  h.w = f2bf(v.w); l.w = f2bf(v.w - bf2f(h.w));
  ((ushort4*)hi)[idx] = h;
  ((ushort4*)lo)[idx] = l;
}

// ---------------------------------------------------------------------------
// Prep 2: w_q/w_k/w_v [1024][128] fp32 -> Wt hi/lo bf16 [384][1024] (B^T layout,
// rows n = p*128 + c).  Tiny (1.5 MB); strided reads hit L2.
// ---------------------------------------------------------------------------
__global__ void cvtw_kernel(const float* __restrict__ wq, const float* __restrict__ wk,
                            const float* __restrict__ wv,
                            unsigned short* __restrict__ Wth, unsigned short* __restrict__ Wtl)
{
  const int n = blockIdx.x;            // 0..383
  const int p = n >> 7, c = n & 127;
  const float* w = (p == 0) ? wq : (p == 1) ? wk : wv;
  for (int k = threadIdx.x; k < DM; k += 256) {
    const float x = w[(size_t)k * DK + c];
    const unsigned short h = f2bf(x);
    Wth[(size_t)n * DM + k] = h;
    Wtl[(size_t)n * DM + k] = f2bf(x - bf2f(h));
  }
}

// ---------------------------------------------------------------------------
// Kernel A: qkv = vin @ [wq|wk|wv] via split-bf16 MFMA (3 products).
// Tile 64x64, BK=64, 4 waves in 2x2, each wave 32x32 (2x2 frags of 16x16x32).
// global_load_lds width-16 staging, linear LDS (m97 structure).
// ---------------------------------------------------------------------------
__global__ __launch_bounds__(256) void proj_mfma(
    const unsigned short* __restrict__ Ah, const unsigned short* __restrict__ Al,
    const unsigned short* __restrict__ Wh, const unsigned short* __restrict__ Wl,
    float* __restrict__ qkv)
{
  __shared__ unsigned short Ash[2][64 * 64];
  __shared__ unsigned short Wsh[2][64 * 64];

  const int r0 = blockIdx.x * 64;      // M tile (8192/64 = 128)
  const int n0 = blockIdx.y * 64;      // N tile (384/64 = 6)
  const int t  = threadIdx.x;
  const int l  = t & 63, w = t >> 6;
  const int wm = w >> 1, wn = w & 1;   // 2x2 wave grid
  const int fr = l & 15, ko = (l >> 4) * 8;

  f32x4 acc[2][2] = {};

  for (int k0 = 0; k0 < DM; k0 += 64) {
    #pragma unroll
    for (int i = 0; i < 2; ++i) {
      const int flat = t + i * 256;          // 512 16B segments per tile
      const int row = flat >> 3, sg = flat & 7;
      const size_t ga = (size_t)(r0 + row) * DM + k0 + sg * 8;
      const size_t gw = (size_t)(n0 + row) * DM + k0 + sg * 8;
      gload16(Ah + ga, &Ash[0][flat * 8]);
      gload16(Al + ga, &Ash[1][flat * 8]);
      gload16(Wh + gw, &Wsh[0][flat * 8]);
      gload16(Wl + gw, &Wsh[1][flat * 8]);
    }
    __syncthreads();

    #pragma unroll
    for (int kk = 0; kk < 2; ++kk) {
      bf16x8 ah[2], al[2], bh[2], bl[2];
      #pragma unroll
      for (int im = 0; im < 2; ++im) {
        const int off = (wm * 32 + im * 16 + fr) * 64 + kk * 32 + ko;
        ah[im] = *(const bf16x8*)&Ash[0][off];
        al[im] = *(const bf16x8*)&Ash[1][off];
      }
      #pragma unroll
      for (int in = 0; in < 2; ++in) {
        const int off = (wn * 32 + in * 16 + fr) * 64 + kk * 32 + ko;
        bh[in] = *(const bf16x8*)&Wsh[0][off];
        bl[in] = *(const bf16x8*)&Wsh[1][off];
      }
      #pragma unroll
      for (int im = 0; im < 2; ++im)
        #pragma unroll
        for (int in = 0; in < 2; ++in) {
          acc[im][in] = __builtin_amdgcn_mfma_f32_16x16x32_bf16(ah[im], bh[in], acc[im][in], 0, 0, 0);
          acc[im][in] = __builtin_amdgcn_mfma_f32_16x16x32_bf16(ah[im], bl[in], acc[im][in], 0, 0, 0);
          acc[im][in] = __builtin_amdgcn_mfma_f32_16x16x32_bf16(al[im], bh[in], acc[im][in], 0, 0, 0);
        }
    }
    __syncthreads();
  }

  // Epilogue: C/D layout col = lane&15, row = (lane>>4)*4 + reg  [m89-verified]
  const int crow = (l >> 4) * 4;
  #pragma unroll
  for (int im = 0; im < 2; ++im)
    #pragma unroll
    for (int in = 0; in < 2; ++in) {
      const int n = n0 + wn * 32 + in * 16 + fr;
      float* dst = qkv + (size_t)(n >> 7) * ((size_t)BS * DK) + (n & 127);
      #pragma unroll
      for (int r = 0; r < 4; ++r) {
        const int m = r0 + wm * 32 + im * 16 + crow + r;
        dst[(size_t)m * DK] = acc[im][in][r];
      }
    }
}

// ---------------------------------------------------------------------------
// Kernel B: raw scores for lower-tri tiles (fp32 vector, float4 LDS reads).
// Full K=128 staged once; 64x64 tile; micro-tile 4x4 (cols tx+16j).
// ---------------------------------------------------------------------------
__global__ __launch_bounds__(256) void scores_kernel(
    const float* __restrict__ qkv, float* __restrict__ att)
{
  const int st = blockIdx.x, qt = blockIdx.y, b = blockIdx.z;
  if (qt < st) return;
  const int q0 = qt * 64, s0 = st * 64;
  const float* qm = qkv + (size_t)b * S * DK;
  const float* km = qkv + (size_t)BS * DK + (size_t)b * S * DK;

  __shared__ float Qs[64][132];
  __shared__ float Ks[64][132];

  const int t  = threadIdx.x;
  const int ty = t >> 4, tx = t & 15;
  float acc[4][4] = {};

  #pragma unroll
  for (int i = 0; i < 8; ++i) {
    const int flat = t + i * 256;           // 2048 float4 per operand
    const int row = flat >> 5, c4 = (flat & 31) * 4;
    *(float4*)&Qs[row][c4] = *(const float4*)&qm[(size_t)(q0 + row) * DK + c4];
    *(float4*)&Ks[row][c4] = *(const float4*)&km[(size_t)(s0 + row) * DK + c4];
  }
  __syncthreads();

  #pragma unroll 2
  for (int kk = 0; kk < DK; kk += 4) {
    float4 a4[4], b4[4];
    #pragma unroll
    for (int i = 0; i < 4; ++i) a4[i] = *(const float4*)&Qs[ty * 4 + i][kk];
    #pragma unroll
    for (int j = 0; j < 4; ++j) b4[j] = *(const float4*)&Ks[tx + 16 * j][kk];
    #pragma unroll
    for (int i = 0; i < 4; ++i)
      #pragma unroll
      for (int j = 0; j < 4; ++j) {
        acc[i][j] += a4[i].x * b4[j].x;
        acc[i][j] += a4[i].y * b4[j].y;
        acc[i][j] += a4[i].z * b4[j].z;
        acc[i][j] += a4[i].w * b4[j].w;
      }
  }

  float* attb = att + (size_t)b * S * S;
  #pragma unroll
  for (int i = 0; i < 4; ++i) {
    const size_t qi = q0 + ty * 4 + i;
    #pragma unroll
    for (int j = 0; j < 4; ++j)
      attb[qi * S + s0 + tx + 16 * j] = acc[i][j] * SCALE;
  }
}

// ---------------------------------------------------------------------------
// Kernel C: column softmax (over q, causal q>=s) — unchanged structure
// ---------------------------------------------------------------------------
__global__ __launch_bounds__(256) void colstats_kernel(
    const float* __restrict__ att, float* __restrict__ pm, float* __restrict__ ps)
{
  const int s  = blockIdx.x * 256 + threadIdx.x;
  const int ch = blockIdx.y, b = blockIdx.z;
  const float* attb = att + (size_t)b * S * S;
  const int qlo = ch * 256, qhi = qlo + 256;
  float m = -INFINITY, sum = 0.f;
  for (int q = qlo; q < qhi; ++q) {
    if (q >= s) {
      const float x  = attb[(size_t)q * S + s];
      const float mn = fmaxf(m, x);
      sum = sum * __expf(m - mn) + __expf(x - mn);
      m = mn;
    }
  }
  const size_t idx = ((size_t)b * 8 + ch) * S + s;
  pm[idx] = m;
  ps[idx] = sum;
}

__global__ void colcombine_kernel(const float* __restrict__ pm, const float* __restrict__ ps,
                                  float* __restrict__ cm, float* __restrict__ cinv)
{
  const int s = blockIdx.x * 256 + threadIdx.x;
  const int b = blockIdx.y;
  float m = -INFINITY;
  for (int ch = 0; ch < 8; ++ch)
    m = fmaxf(m, pm[((size_t)b * 8 + ch) * S + s]);
  float sum = 0.f;
  for (int ch = 0; ch < 8; ++ch) {
    const size_t i = ((size_t)b * 8 + ch) * S + s;
    sum += ps[i] * __expf(pm[i] - m);
  }
  cm[(size_t)b * S + s]   = m;
  cinv[(size_t)b * S + s] = 1.f / sum;
}

__global__ __launch_bounds__(256) void colnorm_kernel(
    float* __restrict__ att, const float* __restrict__ cm, const float* __restrict__ cinv)
{
  const int s  = blockIdx.x * 256 + threadIdx.x;
  const int qt = blockIdx.y, b = blockIdx.z;
  float* attb = att + (size_t)b * S * S;
  const float m   = cm[(size_t)b * S + s];
  const float inv = cinv[(size_t)b * S + s];
  const int q0 = qt * 64;
  for (int q = q0; q < q0 + 64; ++q) {
    const size_t idx = (size_t)q * S + s;
    float x = 0.f;
    if (q >= s) x = __expf(attb[idx] - m) * inv;
    attb[idx] = x;
  }
}

// ---------------------------------------------------------------------------
// Kernel D: out = att @ v (causal; att==0 above diag).  fp32 vector.
// Tile 32q x 128c, micro-tile 4q x 4 contiguous c (float4 stores).
// ---------------------------------------------------------------------------
__global__ __launch_bounds__(256) void out_kernel(
    const float* __restrict__ att, const float* __restrict__ qkv, float* __restrict__ out)
{
  const int qt = blockIdx.x, b = blockIdx.y;
  const int q0 = qt * 32;
  const float* attb = att + (size_t)b * S * S;
  const float* vm   = qkv + 2ull * BS * DK + (size_t)b * S * DK;

  __shared__ float As[32][68];
  __shared__ float Vs[64][132];

  const int t  = threadIdx.x;
  const int ty = t >> 5, tx = t & 31;      // rows ty*4+i, cols tx*4..tx*4+3
  float4 acc4[4] = {};

  for (int s0 = 0; s0 < q0 + 32; s0 += 64) {
    #pragma unroll
    for (int i = 0; i < 2; ++i) {
      const int flat = t + i * 256;        // 512 float4
      const int row = flat >> 4, c4 = (flat & 15) * 4;
      *(float4*)&As[row][c4] = *(const float4*)&attb[(size_t)(q0 + row) * S + s0 + c4];
    }
    #pragma unroll
    for (int i = 0; i < 8; ++i) {
      const int flat = t + i * 256;        // 2048 float4
      const int row = flat >> 5, c4 = (flat & 31) * 4;
      *(float4*)&Vs[row][c4] = *(const float4*)&vm[(size_t)(s0 + row) * DK + c4];
    }
    __syncthreads();

    #pragma unroll 2
    for (int kk = 0; kk < 64; kk += 4) {
      const float4 v0 = *(const float4*)&Vs[kk + 0][tx * 4];
      const float4 v1 = *(const float4*)&Vs[kk + 1][tx * 4];
      const float4 v2 = *(const float4*)&Vs[kk + 2][tx * 4];
      const float4 v3 = *(const float4*)&Vs[kk + 3][tx * 4];
      #pragma unroll
      for (int i = 0; i < 4; ++i) {
        const float4 a4 = *(const float4*)&As[ty * 4 + i][kk];
        acc4[i].x += a4.x * v0.x; acc4[i].y += a4.x * v0.y; acc4[i].z += a4.x * v0.z; acc4[i].w += a4.x * v0.w;
        acc4[i].x += a4.y * v1.x; acc4[i].y += a4.y * v1.y; acc4[i].z += a4.y * v1.z; acc4[i].w += a4.y * v1.w;
        acc4[i].x += a4.z * v2.x; acc4[i].y += a4.z * v2.y; acc4[i].z += a4.z * v2.z; acc4[i].w += a4.z * v2.w;
        acc4[i].x += a4.w * v3.x; acc4[i].y += a4.w * v3.y; acc4[i].z += a4.w * v3.z; acc4[i].w += a4.w * v3.w;
      }
    }
    __syncthreads();
  }

  #pragma unroll
  for (int i = 0; i < 4; ++i)
    *(float4*)&out[((size_t)b * S + q0 + ty * 4 + i) * DK + tx * 4] = acc4[i];
}

// ---------------------------------------------------------------------------
extern "C" void kernel_launch(void* const* d_in, const int* in_sizes, int n_in,
                              void* d_out, int out_size, void* d_ws, size_t ws_size,
                              hipStream_t stream)
{
  const float* vin = (const float*)d_in[0];
  const float* wq  = (const float*)d_in[1];
  const float* wk  = (const float*)d_in[2];
  const float* wv  = (const float*)d_in[3];

  float* out = (float*)d_out;
  float* att = out + (size_t)B * S * DK;     // attention output region (64 MB)

  // bf16 copies live INSIDE the att region (dead before scores_kernel writes it):
  // Ah 16MB + Al 16MB + Wth/Wtl 1.5MB = 33.5MB < 64MB.
  unsigned short* Ah  = (unsigned short*)att;
  unsigned short* Al  = Ah  + (size_t)BS * DM;
  unsigned short* Wth = Al  + (size_t)BS * DM;
  unsigned short* Wtl = Wth + (size_t)384 * DM;

  float* qkv  = (float*)d_ws;                // 3 * BS * 128 fp32
  float* pm   = qkv + 3ull * BS * DK;        // B * 8 * S
  float* ps   = pm + 8ull * B * S;
  float* cm   = ps + 8ull * B * S;
  float* cinv = cm + (size_t)B * S;

  cvt_hilo         <<<dim3(BS * DM / 1024),     256, 0, stream>>>(vin, Ah, Al);
  cvtw_kernel      <<<dim3(384),                256, 0, stream>>>(wq, wk, wv, Wth, Wtl);
  proj_mfma        <<<dim3(128, 6),             256, 0, stream>>>(Ah, Al, Wth, Wtl, qkv);
  scores_kernel    <<<dim3(S / 64, S / 64, B),  256, 0, stream>>>(qkv, att);
  colstats_kernel  <<<dim3(S / 256, 8, B),      256, 0, stream>>>(att, pm, ps);
  colcombine_kernel<<<dim3(S / 256, B),         256, 0, stream>>>(pm, ps, cm, cinv);
  colnorm_kernel   <<<dim3(S / 256, S / 64, B), 256, 0, stream>>>(att, cm, cinv);
  out_kernel       <<<dim3(S / 32, B),          256, 0, stream>>>(att, qkv, out);
}